// Round 12
// baseline (628.979 us; speedup 1.0000x reference)
//
#include <hip/hip_runtime.h>
#include <hip/hip_bf16.h>
#include <math.h>

typedef __attribute__((ext_vector_type(8))) short short8;
typedef __attribute__((ext_vector_type(4))) float f32x4;

// Exact-erf GELU via Abramowitz-Stegun 7.1.26 (|erf err| <= 1.5e-7)
__device__ __forceinline__ float gelu_f(float x) {
  float ax = fabsf(x);
  float z = ax * 0.70710678118654752f;
  float t = __builtin_amdgcn_rcpf(1.0f + 0.3275911f * z);
  float p = t * (0.254829592f +
           t * (-0.284496736f +
           t * (1.421413741f +
           t * (-1.453152027f + t * 1.061405429f))));
  float e = __expf(-z * z);
  float erf_abs = 1.0f - p * e;
  return 0.5f * x + 0.5f * ax * erf_abs;
}

// ---------------------------------------------------------------------------
// Generic conv-as-implicit-GEMM fp32 (branch1 only)
// ---------------------------------------------------------------------------
template<bool TBL, bool GELU, bool TOOUT>
__global__ __launch_bounds__(256) void convgemm_k(
    const float* __restrict__ in, const float* __restrict__ w,
    const float* __restrict__ bns, const float* __restrict__ bnb,
    float* __restrict__ out,
    int Cin, int H, int W, int ks, int stride, int pad, int ls,
    int OH, int OW, int N, int K, int ch0) {
  __shared__ __align__(16) float sA[16][64];
  __shared__ __align__(16) float sB[16][64];
  __shared__ int sTbl[256];
  const int tid = threadIdx.x;
  if (TBL) {
    int kk2 = ks * ks;
    for (int k = tid; k < K; k += 256) {
      int ic = k / kk2, r = k - ic * kk2;
      sTbl[k] = (ic << 16) | ((r / ks) << 8) | (r % ks);
    }
  }
  const int m0 = blockIdx.x * 64, n0 = blockIdx.y * 64;
  const int mm = tid >> 2, kq = tid & 3;
  const int OHW = OH * OW, HW = H * W;
  int m = m0 + mm;
  int bI = m / OHW; int r = m - bI * OHW;
  int oh = r / OW;  int ow = r - oh * OW;
  const int ihBase = oh * stride - pad, iwBase = ow * stride - pad;
  const int inBase = bI * Cin * HW;
  const int tm = tid & 15, tn = tid >> 4;
  float acc[4][4] = {};
  for (int k0 = 0; k0 < K; k0 += 16) {
    __syncthreads();
#pragma unroll
    for (int i = 0; i < 4; ++i) {
      int kk = kq * 4 + i, k = k0 + kk;
      float v = 0.0f;
      if (k < K) {
        int ic, dy, dx;
        if (TBL) {
          int tv = sTbl[k]; ic = tv >> 16; dy = (tv >> 8) & 255; dx = tv & 255;
        } else {
          ic = k >> (2 * ls);
          int r2 = k & ((1 << (2 * ls)) - 1);
          dy = r2 >> ls; dx = r2 & ((1 << ls) - 1);
        }
        int ih = ihBase + dy, iw = iwBase + dx;
        if (ih >= 0 && ih < H && iw >= 0 && iw < W)
          v = in[inBase + ic * HW + ih * W + iw];
      }
      sA[kk][mm] = v;
    }
#pragma unroll
    for (int i = 0; i < 4; ++i) {
      int kk = kq * 4 + i, k = k0 + kk;
      int n = n0 + mm;
      float v = 0.0f;
      if (n < N && k < K) v = w[n * K + k];
      sB[kk][mm] = v;
    }
    __syncthreads();
#pragma unroll
    for (int kk = 0; kk < 16; ++kk) {
      float4 a4 = *(const float4*)&sA[kk][tm * 4];
      float4 b4 = *(const float4*)&sB[kk][tn * 4];
      acc[0][0] += a4.x * b4.x; acc[0][1] += a4.x * b4.y;
      acc[0][2] += a4.x * b4.z; acc[0][3] += a4.x * b4.w;
      acc[1][0] += a4.y * b4.x; acc[1][1] += a4.y * b4.y;
      acc[1][2] += a4.y * b4.z; acc[1][3] += a4.y * b4.w;
      acc[2][0] += a4.z * b4.x; acc[2][1] += a4.z * b4.y;
      acc[2][2] += a4.z * b4.z; acc[2][3] += a4.z * b4.w;
      acc[3][0] += a4.w * b4.x; acc[3][1] += a4.w * b4.y;
      acc[3][2] += a4.w * b4.z; acc[3][3] += a4.w * b4.w;
    }
  }
#pragma unroll
  for (int i = 0; i < 4; ++i) {
    int mI = m0 + tm * 4 + i;
    int bO = mI / OHW; int rr = mI - bO * OHW;
#pragma unroll
    for (int j = 0; j < 4; ++j) {
      int n = n0 + tn * 4 + j;
      if (n < N) {
        float v = acc[i][j] * bns[n] + bnb[n];
        if (GELU) v = gelu_f(v);
        if (TOOUT) {
          out[(bO * OHW + rr) * 768 + ch0 + n] = v;  // OHW==196
        } else {
          int oh2 = rr / OW, ow2 = rr - oh2 * OW;
          out[((bO * N + n) * OH + oh2) * OW + ow2] = v;
        }
      }
    }
  }
}

// ---------------------------------------------------------------------------
// NHWC bf16 implicit-GEMM conv via MFMA, v2:
//  - weights read directly from global (L1/L2-hot, 21-38 KB) as the MFMA
//    A-operand — no sB staging, no second LDS array.
//  - operands swapped (A=weights M=NN, B=pixels N=64): D rows = channels ->
//    each lane stores 4 consecutive channels per pixel as one uint2.
//  Output: NHWC bf16, channel stride NVALID.
// ---------------------------------------------------------------------------
template<int CIN, int KS, int STRIDE, int PAD, int NN, int KP, bool GELU,
         int NVALID = NN>
__global__ __launch_bounds__(256) void nhwc_conv_mfma(
    const __hip_bfloat16* __restrict__ in, const __hip_bfloat16* __restrict__ wb,
    const float* __restrict__ bns, const float* __restrict__ bnb,
    __hip_bfloat16* __restrict__ out, int Hin, int Win, int OW, int OHW) {
  constexpr int K = KS * KS * CIN;
  constexpr int LROW = KP + 8;
  __shared__ __align__(16) __hip_bfloat16 sA[64][LROW];
  const int tid = threadIdx.x;
  const float4 f4z = make_float4(0.f, 0.f, 0.f, 0.f);
  if constexpr (CIN == 4) {
    const int m = tid & 63, tg = tid >> 6;
    const int mg = blockIdx.x * 64 + m;
    const int bI = mg / OHW; int pix = mg - bI * OHW;
    const int oh = pix / OW, ow = pix - oh * OW;
    for (int dy = tg; dy < KS; dy += 4) {
      const int ih = oh * STRIDE - PAD + dy;
      __hip_bfloat16* dst = &sA[m][dy * KS * 4];
#pragma unroll
      for (int j = 0; j < KS; ++j) {
        int iw = ow * STRIDE - PAD + j;
        uint2 v = make_uint2(0u, 0u);
        if (ih >= 0 && ih < Hin && iw >= 0 && iw < Win)
          v = *(const uint2*)(in + (((size_t)bI * Hin + ih) * Win + iw) * 4);
        *(uint2*)(dst + j * 4) = v;
      }
    }
    if (tg == 3) {
      for (int c = K; c < KP; c += 4) *(uint2*)&sA[m][c] = make_uint2(0u, 0u);
    }
  } else {
    const int m = tid & 63, dy = tid >> 6;
    const int mg = blockIdx.x * 64 + m;
    const int bI = mg / OHW; int pix = mg - bI * OHW;
    const int oh = pix / OW, ow = pix - oh * OW;
    if (dy < KS) {
      const int ih = oh * STRIDE - PAD + dy;
      __hip_bfloat16* dst = &sA[m][dy * KS * CIN];
      if (ih < 0 || ih >= Hin) {
#pragma unroll
        for (int i = 0; i < KS * CIN / 8; ++i) ((float4*)dst)[i] = f4z;
      } else {
        const __hip_bfloat16* srow = in + ((size_t)bI * Hin + ih) * Win * CIN;
#pragma unroll
        for (int j = 0; j < KS; ++j) {
          int iw = ow * STRIDE - PAD + j;
          if (PAD > 0 && (iw < 0 || iw >= Win)) {
#pragma unroll
            for (int i = 0; i < CIN / 8; ++i) ((float4*)(dst + j * CIN))[i] = f4z;
          } else {
            const float4* s4 = (const float4*)(srow + (size_t)iw * CIN);
#pragma unroll
            for (int i = 0; i < CIN / 8; ++i) ((float4*)(dst + j * CIN))[i] = s4[i];
          }
        }
      }
    } else if (K < KP) {
#pragma unroll
      for (int c = K; c < KP + 8; c += 8) *(float4*)&sA[m][c] = f4z;
    }
  }
  __syncthreads();
  constexpr int NT = NN / 16;
  const int wave = tid >> 6, lane = tid & 63;
  const int fm = lane & 15, quad = lane >> 4;
  const int p = wave * 16 + fm;   // pixel within block (B-operand col)
  f32x4 acc[NT] = {};
#pragma unroll
  for (int ks = 0; ks < KP / 32; ++ks) {
    short8 hb = *(const short8*)&sA[p][ks * 32 + quad * 8];
#pragma unroll
    for (int m = 0; m < NT; ++m) {
      short8 wa = *(const short8*)(wb + (size_t)(m * 16 + fm) * KP + ks * 32 + quad * 8);
      acc[m] = __builtin_amdgcn_mfma_f32_16x16x32_bf16(wa, hb, acc[m], 0, 0, 0);
    }
  }
  // epilogue: lane = 1 pixel (wave*16+fm), channels m*16+quad*4..+3 -> uint2
  const int mg0 = blockIdx.x * 64 + p;
  const int bI = mg0 / OHW, pix = mg0 - bI * OHW;
  __hip_bfloat16* obase = out + ((size_t)bI * OHW + pix) * NVALID;
#pragma unroll
  for (int m = 0; m < NT; ++m) {
    int ch0m = m * 16 + quad * 4;
    if (ch0m < NVALID) {
      __hip_bfloat16 vb[4];
#pragma unroll
      for (int e = 0; e < 4; ++e) {
        int ch = ch0m + e;
        float v = acc[m][e] * bns[ch] + bnb[ch];
        if (GELU) v = gelu_f(v);
        vb[e] = (__hip_bfloat16)v;
      }
      *(uint2*)&obase[ch0m] = *(uint2*)vb;
    }
  }
}

// ---------------------------------------------------------------------------
// Fused RegionLayerDW for region2 (R10 v3, unchanged — validated)
// ---------------------------------------------------------------------------
__global__ __launch_bounds__(256, 4) void region2_mfma(
    const __hip_bfloat16* __restrict__ in, const float* __restrict__ dww,
    const float* __restrict__ s1v, const float* __restrict__ b1v,
    const __hip_bfloat16* __restrict__ pwb,
    const float* __restrict__ s2v, const float* __restrict__ b2v,
    __hip_bfloat16* __restrict__ out) {
  __shared__ __align__(16) __hip_bfloat16 sIn[10][10][56];
  __shared__ __align__(16) __hip_bfloat16 sH[64][64];
  __shared__ __align__(16) __hip_bfloat16 sW[48][64];
  __shared__ float sDW[48][9];
  __shared__ float sS1[48], sB1[48], sS2[48], sB2[48];
  const int t = blockIdx.x, sb = blockIdx.y, b = blockIdx.z;
  const int gy = t >> 2, gx = t & 3;
  const int py0 = (sb / 7) * 8, px0 = (sb % 7) * 8;
  const int Y0 = gy * 56, X0 = gx * 56;
  const int tid = threadIdx.x;
  for (int i = tid; i < 48 * 8; i += 256) {
    int n = i >> 3, g = i & 7;
    float4 v = *(const float4*)&pwb[(size_t)(t * 48 + n) * 64 + g * 8];
    *(float4*)&sW[n][((g ^ (n & 7)) * 8)] = v;
  }
  for (int i = tid; i < 432; i += 256) ((float*)sDW)[i] = dww[t * 432 + i];
  if (tid < 48) {
    sS1[tid] = s1v[t * 48 + tid]; sB1[tid] = b1v[t * 48 + tid];
    sS2[tid] = s2v[t * 48 + tid]; sB2[tid] = b2v[t * 48 + tid];
  }
  for (int i = tid; i < 600; i += 256) {
    int px = i / 6, grp = i - px * 6;
    int r = px / 10, c = px - r * 10;
    int ly = py0 + r - 1, lx = px0 + c - 1;
    uint4 v = make_uint4(0u, 0u, 0u, 0u);
    if (ly >= 0 && ly < 56 && lx >= 0 && lx < 56)
      v = *(const uint4*)(in + (((size_t)b * 224 + Y0 + ly) * 224 + X0 + lx) * 48 +
                          grp * 8);
    *(uint4*)&sIn[r][c][grp * 8] = v;
  }
  __syncthreads();
  if (tid < 192) {
    const int cg = tid >> 4;
    const int rem = tid & 15;
    const int col = rem >> 1;
    const int rh = rem & 1;
    const int ch0 = cg * 4;
    float wv[4][9], s14[4], b14[4];
#pragma unroll
    for (int c4 = 0; c4 < 4; ++c4) {
#pragma unroll
      for (int q = 0; q < 9; ++q) wv[c4][q] = sDW[ch0 + c4][q];
      s14[c4] = sS1[ch0 + c4]; b14[c4] = sB1[ch0 + c4];
    }
    float win[3][12];
#pragma unroll
    for (int rr = 0; rr < 6; ++rr) {
      int r = rh * 4 + rr;
      float* wr = win[rr % 3];
#pragma unroll
      for (int cc = 0; cc < 3; ++cc) {
        uint2 u = *(const uint2*)&sIn[r][col + cc][ch0];
        wr[cc * 4 + 0] = __uint_as_float(u.x << 16);
        wr[cc * 4 + 1] = __uint_as_float(u.x & 0xffff0000u);
        wr[cc * 4 + 2] = __uint_as_float(u.y << 16);
        wr[cc * 4 + 3] = __uint_as_float(u.y & 0xffff0000u);
      }
      if (rr >= 2) {
        const float* ra = win[(rr - 2) % 3];
        const float* rb = win[(rr - 1) % 3];
        const float* rc = win[rr % 3];
        int px = (rh * 4 + rr - 2) * 8 + col;
        __hip_bfloat16 hv[4];
#pragma unroll
        for (int c4 = 0; c4 < 4; ++c4) {
          float a = ra[c4] * wv[c4][0] + ra[4 + c4] * wv[c4][1] + ra[8 + c4] * wv[c4][2]
                  + rb[c4] * wv[c4][3] + rb[4 + c4] * wv[c4][4] + rb[8 + c4] * wv[c4][5]
                  + rc[c4] * wv[c4][6] + rc[4 + c4] * wv[c4][7] + rc[8 + c4] * wv[c4][8];
          hv[c4] = (__hip_bfloat16)gelu_f(a * s14[c4] + b14[c4]);
        }
        *(uint2*)&sH[px][((cg >> 1) ^ (px & 7)) * 8 + (cg & 1) * 4] = *(uint2*)hv;
      }
    }
  } else {
    for (int i = tid - 192; i < 128; i += 64) {
      int px = i >> 1, g = 6 + (i & 1);
      *(float4*)&sH[px][(g ^ (px & 7)) * 8] = make_float4(0.f, 0.f, 0.f, 0.f);
    }
  }
  __syncthreads();
  const int wave = tid >> 6, lane = tid & 63;
  const int fm = lane & 15, quad = lane >> 4;
  const int px = wave * 16 + fm, pxk = px & 7;
  f32x4 acc[3] = {};
#pragma unroll
  for (int ks = 0; ks < 2; ++ks) {
    short8 hb = *(const short8*)&sH[px][((ks * 4 + quad) ^ pxk) * 8];
#pragma unroll
    for (int m = 0; m < 3; ++m) {
      int wr = m * 16 + fm;
      short8 wa = *(const short8*)&sW[wr][((ks * 4 + quad) ^ (wr & 7)) * 8];
      acc[m] = __builtin_amdgcn_mfma_f32_16x16x32_bf16(wa, hb, acc[m], 0, 0, 0);
    }
  }
  const int row = px >> 3, col = px & 7;
  __hip_bfloat16* obase =
      out + (((size_t)b * 224 + Y0 + py0 + row) * 224 + X0 + px0 + col) * 48;
#pragma unroll
  for (int m = 0; m < 3; ++m) {
    int ch0m = m * 16 + quad * 4;
    uint2 ru = *(const uint2*)&sIn[row + 1][col + 1][ch0m];
    float res[4];
    res[0] = __uint_as_float(ru.x << 16);
    res[1] = __uint_as_float(ru.x & 0xffff0000u);
    res[2] = __uint_as_float(ru.y << 16);
    res[3] = __uint_as_float(ru.y & 0xffff0000u);
    __hip_bfloat16 vb[4];
#pragma unroll
    for (int e = 0; e < 4; ++e) {
      int ch = ch0m + e;
      float v = acc[m][e] * sS2[ch] + sB2[ch] + res[e];
      vb[e] = (__hip_bfloat16)gelu_f(v);
    }
    *(uint2*)&obase[ch0m] = *(uint2*)vb;
  }
}

// ---------------------------------------------------------------------------
// Fused RegionLayerDW for region1 (R11, unchanged — validated)
// ---------------------------------------------------------------------------
__global__ __launch_bounds__(256, 4) void region1_mfma(
    const __hip_bfloat16* __restrict__ in, const float* __restrict__ dww,
    const float* __restrict__ s1v, const float* __restrict__ b1v,
    const __hip_bfloat16* __restrict__ pwb,
    const float* __restrict__ s2v, const float* __restrict__ b2v,
    __hip_bfloat16* __restrict__ out) {
  __shared__ __align__(16) __hip_bfloat16 sIn[10][10][24];
  __shared__ __align__(16) __hip_bfloat16 sH[64][32];
  __shared__ __align__(16) __hip_bfloat16 sW[32][32];
  __shared__ float sDW[24][9];
  __shared__ float sS1[24], sB1[24], sS2[24], sB2[24];
  const int t = blockIdx.x, sb = blockIdx.y, b = blockIdx.z;
  const int gy = t / 7, gx = t % 7;
  const int py0 = (sb >> 2) * 8, px0 = (sb & 3) * 8;
  const int Y0 = gy * 32, X0 = gx * 32;
  const int tid = threadIdx.x;
  for (int i = tid; i < 128; i += 256) {
    int n = i >> 2, g = i & 3;
    float4 v = make_float4(0.f, 0.f, 0.f, 0.f);
    if (n < 24) v = *(const float4*)&pwb[(size_t)(t * 24 + n) * 32 + g * 8];
    *(float4*)&sW[n][(g ^ (n & 3)) * 8] = v;
  }
  for (int i = tid; i < 216; i += 256) ((float*)sDW)[i] = dww[t * 216 + i];
  if (tid < 24) {
    sS1[tid] = s1v[t * 24 + tid]; sB1[tid] = b1v[t * 24 + tid];
    sS2[tid] = s2v[t * 24 + tid]; sB2[tid] = b2v[t * 24 + tid];
  }
  for (int i = tid; i < 300; i += 256) {
    int px = i / 3, grp = i - px * 3;
    int r = px / 10, c = px - r * 10;
    int ly = py0 + r - 1, lx = px0 + c - 1;
    uint4 v = make_uint4(0u, 0u, 0u, 0u);
    if (ly >= 0 && ly < 32 && lx >= 0 && lx < 32)
      v = *(const uint4*)(in + (((size_t)b * 224 + Y0 + ly) * 224 + X0 + lx) * 24 +
                          grp * 8);
    *(uint4*)&sIn[r][c][grp * 8] = v;
  }
  __syncthreads();
  if (tid < 192) {
    const int cg = tid >> 5;
    const int rem = tid & 31;
    const int col = rem >> 2;
    const int rq = rem & 3;
    const int ch0 = cg * 4;
    float wv[4][9], s14[4], b14[4];
#pragma unroll
    for (int c4 = 0; c4 < 4; ++c4) {
#pragma unroll
      for (int q = 0; q < 9; ++q) wv[c4][q] = sDW[ch0 + c4][q];
      s14[c4] = sS1[ch0 + c4]; b14[c4] = sB1[ch0 + c4];
    }
    float win[3][12];
#pragma unroll
    for (int rr = 0; rr < 4; ++rr) {
      int r = rq * 2 + rr;
      float* wr = win[rr % 3];
#pragma unroll
      for (int cc = 0; cc < 3; ++cc) {
        uint2 u = *(const uint2*)&sIn[r][col + cc][ch0];
        wr[cc * 4 + 0] = __uint_as_float(u.x << 16);
        wr[cc * 4 + 1] = __uint_as_float(u.x & 0xffff0000u);
        wr[cc * 4 + 2] = __uint_as_float(u.y << 16);
        wr[cc * 4 + 3] = __uint_as_float(u.y & 0xffff0000u);
      }
      if (rr >= 2) {
        const float* ra = win[(rr - 2) % 3];
        const float* rb = win[(rr - 1) % 3];
        const float* rc = win[rr % 3];
        int px = (rq * 2 + rr - 2) * 8 + col;
        __hip_bfloat16 hv[4];
#pragma unroll
        for (int c4 = 0; c4 < 4; ++c4) {
          float a = ra[c4] * wv[c4][0] + ra[4 + c4] * wv[c4][1] + ra[8 + c4] * wv[c4][2]
                  + rb[c4] * wv[c4][3] + rb[4 + c4] * wv[c4][4] + rb[8 + c4] * wv[c4][5]
                  + rc[c4] * wv[c4][6] + rc[4 + c4] * wv[c4][7] + rc[8 + c4] * wv[c4][8];
          hv[c4] = (__hip_bfloat16)gelu_f(a * s14[c4] + b14[c4]);
        }
        *(uint2*)&sH[px][((cg >> 1) ^ (px & 3)) * 8 + (cg & 1) * 4] = *(uint2*)hv;
      }
    }
  } else {
    int px = tid - 192;
    *(float4*)&sH[px][(3 ^ (px & 3)) * 8] = make_float4(0.f, 0.f, 0.f, 0.f);
  }
  __syncthreads();
  const int wave = tid >> 6, lane = tid & 63;
  const int fm = lane & 15, quad = lane >> 4;
  const int px = wave * 16 + fm;
  short8 hb = *(const short8*)&sH[px][(quad ^ (px & 3)) * 8];
  f32x4 acc[2] = {};
#pragma unroll
  for (int m = 0; m < 2; ++m) {
    int wr = m * 16 + fm;
    short8 wa = *(const short8*)&sW[wr][(quad ^ (wr & 3)) * 8];
    acc[m] = __builtin_amdgcn_mfma_f32_16x16x32_bf16(wa, hb, acc[m], 0, 0, 0);
  }
  const int row = px >> 3, col = px & 7;
  __hip_bfloat16* obase =
      out + (((size_t)b * 224 + Y0 + py0 + row) * 224 + X0 + px0 + col) * 24;
#pragma unroll
  for (int m = 0; m < 2; ++m) {
    int ch0m = m * 16 + quad * 4;
    if (ch0m < 24) {
      uint2 ru = *(const uint2*)&sIn[row + 1][col + 1][ch0m];
      float res[4];
      res[0] = __uint_as_float(ru.x << 16);
      res[1] = __uint_as_float(ru.x & 0xffff0000u);
      res[2] = __uint_as_float(ru.y << 16);
      res[3] = __uint_as_float(ru.y & 0xffff0000u);
      __hip_bfloat16 vb[4];
#pragma unroll
      for (int e = 0; e < 4; ++e) {
        int ch = ch0m + e;
        float v = acc[m][e] * sS2[ch] + sB2[ch] + res[e];
        vb[e] = (__hip_bfloat16)gelu_f(v);
      }
      *(uint2*)&obase[ch0m] = *(uint2*)vb;
    }
  }
}

// ---------------------------------------------------------------------------
// Patch-GEMM via MFMA (b3 + branch2-conv2). Unchanged.
// ---------------------------------------------------------------------------
template<int PS, int IMGW, int KTOT, int KSL, bool ATOMIC>
__global__ __launch_bounds__(256) void patch_gemm_mfma(
    const __hip_bfloat16* __restrict__ A, const __hip_bfloat16* __restrict__ Wb,
    const float* __restrict__ scale, const float* __restrict__ bias,
    float* __restrict__ out, int M, int ch0) {
  constexpr int RUN = PS * 48;
  __shared__ __align__(16) __hip_bfloat16 sA[64][64];
  __shared__ __align__(16) __hip_bfloat16 sB[64][64];
  const int tid = threadIdx.x;
  const int m0 = blockIdx.x * 64, n0 = blockIdx.y * 64;
  const int kBase = blockIdx.z * KSL;
  const int mi = tid >> 2, seg = tid & 3;
  int m = m0 + mi; int mc = (m < M) ? m : (M - 1);
  int bI = mc / 196; int r = mc - bI * 196;
  int oh = r / 14, ow = r - oh * 14;
  const __hip_bfloat16* Abase =
      A + (((size_t)bI * IMGW + oh * PS) * IMGW + ow * PS) * 48;
  const __hip_bfloat16* Wrow = Wb + (size_t)(n0 + mi) * KTOT;
  const int wave = tid >> 6, lane = tid & 63;
  const int wm = (wave & 1) * 32, wn = (wave >> 1) * 32;
  const int fm = lane & 15, quad = lane >> 4;
  const int sw = fm & 7;
  f32x4 acc[2][2] = {};
  for (int k0 = kBase; k0 < kBase + KSL; k0 += 64) {
    int dy = k0 / RUN, rem = k0 - dy * RUN;
    __syncthreads();
    {
      const __hip_bfloat16* p = Abase + (size_t)dy * IMGW * 48 + rem + seg * 16;
      float4 v0 = *(const float4*)p;
      float4 v1 = *(const float4*)(p + 8);
      int key = mi & 7;
      *(float4*)&sA[mi][((seg * 2) ^ key) * 8] = v0;
      *(float4*)&sA[mi][((seg * 2 + 1) ^ key) * 8] = v1;
      const __hip_bfloat16* q = Wrow + k0 + seg * 16;
      float4 w0 = *(const float4*)q;
      float4 w1 = *(const float4*)(q + 8);
      *(float4*)&sB[mi][((seg * 2) ^ key) * 8] = w0;
      *(float4*)&sB[mi][((seg * 2 + 1) ^ key) * 8] = w1;
    }
    __syncthreads();
#pragma unroll
    for (int ks = 0; ks < 2; ++ks) {
      int cg = (ks * 4 + quad) ^ sw;
#pragma unroll
      for (int i = 0; i < 2; ++i) {
        short8 a = *(const short8*)&sA[wm + i * 16 + fm][cg * 8];
#pragma unroll
        for (int j = 0; j < 2; ++j) {
          short8 b = *(const short8*)&sB[wn + j * 16 + fm][cg * 8];
          acc[i][j] = __builtin_amdgcn_mfma_f32_16x16x32_bf16(a, b, acc[i][j], 0, 0, 0);
        }
      }
    }
  }
#pragma unroll
  for (int i = 0; i < 2; ++i) {
#pragma unroll
    for (int j = 0; j < 2; ++j) {
      int gn = n0 + wn + j * 16 + fm;
      float sc = scale[gn];
#pragma unroll
      for (int e = 0; e < 4; ++e) {
        int gm = m0 + wm + i * 16 + quad * 4 + e;
        if (gm < M) {
          if (ATOMIC)
            atomicAdd(&out[(size_t)gm * 768 + ch0 + gn], acc[i][j][e] * sc);
          else
            out[(size_t)gm * 768 + ch0 + gn] = acc[i][j][e] * sc + bias[gn];
        }
      }
    }
  }
}

__global__ void init_b3(float* __restrict__ out, const float* __restrict__ bias) {
  int i = blockIdx.x * 256 + threadIdx.x;
  if (i < 16 * 196 * 256) {
    int n = i & 255, bp = i >> 8;
    out[bp * 768 + 512 + n] = bias[n];
  }
}

// OIHW fp32 -> [N][KP] bf16 with k=(dy*ks+dx)*Cin+ic, zero-padded to KP
__global__ void reorder_w_k(const float* __restrict__ w, __hip_bfloat16* __restrict__ o,
                            int N, int Cin, int ks, int KP) {
  int i = blockIdx.x * 256 + threadIdx.x;
  if (i >= N * KP) return;
  int n = i / KP, k = i - n * KP;
  float v = 0.f;
  int K = ks * ks * Cin;
  if (k < K) {
    int dy = k / (ks * Cin); int r = k - dy * ks * Cin;
    int dx = r / Cin, ic = r - dx * Cin;
    v = w[((n * Cin + ic) * ks + dy) * ks + dx];
  }
  o[i] = (__hip_bfloat16)v;
}

// OIHW fp32 -> [Nout][KP] bf16 with channel padding
__global__ void reorder_w4(const float* __restrict__ w, __hip_bfloat16* __restrict__ o,
                           int Nout, int Nreal, int Cp, int Cr, int ks, int KP) {
  int i = blockIdx.x * 256 + threadIdx.x;
  if (i >= Nout * KP) return;
  int n = i / KP, k = i - n * KP;
  float v = 0.f;
  if (n < Nreal && k < ks * ks * Cp) {
    int dy = k / (ks * Cp); int r = k - dy * ks * Cp;
    int dx = r / Cp, ic = r - dx * Cp;
    if (ic < Cr) v = w[((n * Cr + ic) * ks + dy) * ks + dx];
  }
  o[i] = (__hip_bfloat16)v;
}

// region2 pw weights [16][48][48] fp32 -> [16][48][64] bf16 (K-padded)
__global__ void rw_pw(const float* __restrict__ pw, __hip_bfloat16* __restrict__ o) {
  int i = blockIdx.x * 256 + threadIdx.x;
  if (i >= 16 * 48 * 64) return;
  int t = i / 3072, r = i - t * 3072;
  int n = r >> 6, k = r & 63;
  float v = (k < 48) ? pw[(t * 48 + n) * 48 + k] : 0.f;
  o[i] = (__hip_bfloat16)v;
}

// region1 pw weights [49][24][24] fp32 -> [49][24][32] bf16 (K-padded)
__global__ void rw_pw1(const float* __restrict__ pw, __hip_bfloat16* __restrict__ o) {
  int i = blockIdx.x * 256 + threadIdx.x;
  if (i >= 49 * 24 * 32) return;
  int t = i / 768, r = i - t * 768;
  int n = r >> 5, k = r & 31;
  float v = (k < 24) ? pw[(t * 24 + n) * 24 + k] : 0.f;
  o[i] = (__hip_bfloat16)v;
}

// x [16,3,224,224] fp32 -> [16,224,224,4] bf16 (ch3 = 0)
__global__ void xcvt(const float* __restrict__ x, __hip_bfloat16* __restrict__ o) {
  int i = blockIdx.x * 256 + threadIdx.x;
  if (i >= 802816) return;
  int b = i / 50176, p = i - b * 50176;
  const float* src = x + (size_t)b * 150528 + p;
  __hip_bfloat16 v[4];
  v[0] = (__hip_bfloat16)src[0];
  v[1] = (__hip_bfloat16)src[50176];
  v[2] = (__hip_bfloat16)src[100352];
  v[3] = (__hip_bfloat16)0.0f;
  *(uint2*)&o[(size_t)i * 4] = *(uint2*)v;
}

// ---------------------------------------------------------------------------
extern "C" void kernel_launch(void* const* d_in, const int* in_sizes, int n_in,
                              void* d_out, int out_size, void* d_ws, size_t ws_size,
                              hipStream_t stream) {
  const float* x     = (const float*)d_in[0];
  const float* r1_w  = (const float*)d_in[1];
  const float* r1_s  = (const float*)d_in[2];
  const float* r1_b  = (const float*)d_in[3];
  const float* r1_dw = (const float*)d_in[4];
  const float* r1_s1 = (const float*)d_in[5];
  const float* r1_b1 = (const float*)d_in[6];
  const float* r1_pw = (const float*)d_in[7];
  const float* r1_s2 = (const float*)d_in[8];
  const float* r1_b2 = (const float*)d_in[9];
  const float* r2_w  = (const float*)d_in[10];
  const float* r2_s  = (const float*)d_in[11];
  const float* r2_b  = (const float*)d_in[12];
  const float* r2_dw = (const float*)d_in[13];
  const float* r2_s1 = (const float*)d_in[14];
  const float* r2_b1 = (const float*)d_in[15];
  const float* r2_pw = (const float*)d_in[16];
  const float* r2_s2 = (const float*)d_in[17];
  const float* r2_b2 = (const float*)d_in[18];
  const float* h1_w1 = (const float*)d_in[19];
  const float* h1_s1 = (const float*)d_in[20];
  const float* h1_b1 = (const float*)d_in[21];
  const float* h1_w2 = (const float*)d_in[22];
  const float* h1_s2 = (const float*)d_in[23];
  const float* h1_b2 = (const float*)d_in[24];
  const float* h1_w3 = (const float*)d_in[25];
  const float* h1_s3 = (const float*)d_in[26];
  const float* h1_b3 = (const float*)d_in[27];
  const float* h2_w1 = (const float*)d_in[28];
  const float* h2_s1 = (const float*)d_in[29];
  const float* h2_b1 = (const float*)d_in[30];
  const float* h2_w2 = (const float*)d_in[31];
  const float* h2_s2 = (const float*)d_in[32];
  const float* h2_b2 = (const float*)d_in[33];
  const float* h3_w  = (const float*)d_in[34];
  const float* h3_s  = (const float*)d_in[35];
  const float* h3_b  = (const float*)d_in[36];
  float* out = (float*)d_out;

  // Workspace (float-slot offsets). FULL-BATCH, peak ~223 MB < 256 MiB.
  float* F = (float*)d_ws;
  __hip_bfloat16* R1b   = (__hip_bfloat16*)F;                    // [16,224,224,24]
  __hip_bfloat16* C5b   = (__hip_bfloat16*)(F + 9633792);        // [16,224,224,24]
  __hip_bfloat16* T1b   = (__hip_bfloat16*)(F + 9633792);        // [16,224,224,48]
  __hip_bfloat16* T2b   = (__hip_bfloat16*)(F + 28901376);       // [16,224,224,48]
  __hip_bfloat16* h3wb  = (__hip_bfloat16*)(F + 48168960);       // [256][12288]
  __hip_bfloat16* r2wb  = (__hip_bfloat16*)(F + 49741824);       // [48][224]
  __hip_bfloat16* h2w1b = (__hip_bfloat16*)(F + 49747200);       // [48][384]
  __hip_bfloat16* pw2wb = (__hip_bfloat16*)(F + 49756416);       // [16][48][64]
  __hip_bfloat16* r1wb  = (__hip_bfloat16*)(F + 49780992);       // [32][128]
  __hip_bfloat16* h2w2b = (__hip_bfloat16*)(F + 49783040);       // [256][768]
  __hip_bfloat16* xb    = (__hip_bfloat16*)(F + 49881344);       // [16,224,224,4]
  __hip_bfloat16* S1b   = (__hip_bfloat16*)(F + 51486976);       // [16,56,56,48]
  float* S1             = F + 52691200;                          // [16,48,56,56]
  float* S2             = F + 55099648;                          // [16,48,28,28]
  __hip_bfloat16* pw1wb = (__hip_bfloat16*)(F + 55701760);       // [49][24][32]

  dim3 blk(256);

  // ---- input conversion + weight reorders
  xcvt<<<dim3(3136), blk, 0, stream>>>(x, xb);
  reorder_w_k<<<dim3(12288), blk, 0, stream>>>(h3_w, h3wb, 256, 48, 16, 12288);
  reorder_w_k<<<dim3(42), blk, 0, stream>>>(r2_w, r2wb, 48, 24, 3, 224);
  reorder_w_k<<<dim3(72), blk, 0, stream>>>(h2_w1, h2w1b, 48, 24, 4, 384);
  reorder_w_k<<<dim3(768), blk, 0, stream>>>(h2_w2, h2w2b, 256, 48, 4, 768);
  reorder_w4<<<dim3(16), blk, 0, stream>>>(r1_w, r1wb, 32, 24, 4, 3, 5, 128);
  rw_pw<<<dim3(192), blk, 0, stream>>>(r2_pw, pw2wb);
  rw_pw1<<<dim3(147), blk, 0, stream>>>(r1_pw, pw1wb);

  // ---- region1 chain, FULL BATCH: conv5 MFMA -> C5b NHWC bf16, region1 -> R1b
  nhwc_conv_mfma<4, 5, 1, 2, 32, 128, true, 24><<<dim3(12544), blk, 0, stream>>>(
      xb, r1wb, r1_s, r1_b, C5b, 224, 224, 224, 50176);
  region1_mfma<<<dim3(49, 16, 16), blk, 0, stream>>>(
      C5b, r1_dw, r1_s1, r1_b1, pw1wb, r1_s2, r1_b2, R1b);
  // ---- branch2: R1b -> S1b bf16 NHWC -> out[ch 256:512]
  nhwc_conv_mfma<24, 4, 4, 0, 48, 384, true><<<dim3(784), blk, 0, stream>>>(
      R1b, h2w1b, h2_s1, h2_b1, S1b, 224, 224, 56, 3136);
  patch_gemm_mfma<4, 56, 768, 768, false><<<dim3(49, 4, 1), blk, 0, stream>>>(
      S1b, h2w2b, h2_s2, h2_b2, out, 3136, 256);
  // ---- branch1: x -> S1 -> S2 -> out[ch 0:256] (fp32, small)
  convgemm_k<false, true, false><<<dim3(784, 1), blk, 0, stream>>>(
      x, h1_w1, h1_s1, h1_b1, S1, 3, 224, 224, 4, 4, 0, 2, 56, 56, 48, 48, 0);
  convgemm_k<false, true, false><<<dim3(196, 1), blk, 0, stream>>>(
      S1, h1_w2, h1_s2, h1_b2, S2, 48, 56, 56, 2, 2, 0, 1, 28, 28, 48, 192, 0);
  convgemm_k<false, false, true><<<dim3(49, 4), blk, 0, stream>>>(
      S2, h1_w3, h1_s3, h1_b3, out, 48, 28, 28, 2, 2, 0, 1, 14, 14, 256, 192, 0);
  // ---- branch3 FULL BATCH: conv3 -> region2 -> b3 patch-GEMM (split-K)
  init_b3<<<dim3(3136), blk, 0, stream>>>(out, h3_b);
  nhwc_conv_mfma<24, 3, 1, 1, 48, 224, true><<<dim3(12544), blk, 0, stream>>>(
      R1b, r2wb, r2_s, r2_b, T1b, 224, 224, 224, 50176);
  region2_mfma<<<dim3(16, 49, 16), blk, 0, stream>>>(
      T1b, r2_dw, r2_s1, r2_b1, pw2wb, r2_s2, r2_b2, T2b);
  patch_gemm_mfma<16, 224, 12288, 1536, true><<<dim3(49, 4, 8), blk, 0, stream>>>(
      T2b, h3wb, h3_s, h3_b, out, 3136, 512);
  (void)in_sizes; (void)n_in; (void)out_size; (void)ws_size;
}

// Round 13
// 616.943 us; speedup vs baseline: 1.0195x; 1.0195x over previous
//
#include <hip/hip_runtime.h>
#include <hip/hip_bf16.h>
#include <math.h>

typedef __attribute__((ext_vector_type(8))) short short8;
typedef __attribute__((ext_vector_type(4))) float f32x4;

// Exact-erf GELU via Abramowitz-Stegun 7.1.26 (|erf err| <= 1.5e-7)
__device__ __forceinline__ float gelu_f(float x) {
  float ax = fabsf(x);
  float z = ax * 0.70710678118654752f;
  float t = __builtin_amdgcn_rcpf(1.0f + 0.3275911f * z);
  float p = t * (0.254829592f +
           t * (-0.284496736f +
           t * (1.421413741f +
           t * (-1.453152027f + t * 1.061405429f))));
  float e = __expf(-z * z);
  float erf_abs = 1.0f - p * e;
  return 0.5f * x + 0.5f * ax * erf_abs;
}

// ---------------------------------------------------------------------------
// Generic conv-as-implicit-GEMM fp32 (branch1 only)
// ---------------------------------------------------------------------------
template<bool TBL, bool GELU, bool TOOUT>
__global__ __launch_bounds__(256) void convgemm_k(
    const float* __restrict__ in, const float* __restrict__ w,
    const float* __restrict__ bns, const float* __restrict__ bnb,
    float* __restrict__ out,
    int Cin, int H, int W, int ks, int stride, int pad, int ls,
    int OH, int OW, int N, int K, int ch0) {
  __shared__ __align__(16) float sA[16][64];
  __shared__ __align__(16) float sB[16][64];
  __shared__ int sTbl[256];
  const int tid = threadIdx.x;
  if (TBL) {
    int kk2 = ks * ks;
    for (int k = tid; k < K; k += 256) {
      int ic = k / kk2, r = k - ic * kk2;
      sTbl[k] = (ic << 16) | ((r / ks) << 8) | (r % ks);
    }
  }
  const int m0 = blockIdx.x * 64, n0 = blockIdx.y * 64;
  const int mm = tid >> 2, kq = tid & 3;
  const int OHW = OH * OW, HW = H * W;
  int m = m0 + mm;
  int bI = m / OHW; int r = m - bI * OHW;
  int oh = r / OW;  int ow = r - oh * OW;
  const int ihBase = oh * stride - pad, iwBase = ow * stride - pad;
  const int inBase = bI * Cin * HW;
  const int tm = tid & 15, tn = tid >> 4;
  float acc[4][4] = {};
  for (int k0 = 0; k0 < K; k0 += 16) {
    __syncthreads();
#pragma unroll
    for (int i = 0; i < 4; ++i) {
      int kk = kq * 4 + i, k = k0 + kk;
      float v = 0.0f;
      if (k < K) {
        int ic, dy, dx;
        if (TBL) {
          int tv = sTbl[k]; ic = tv >> 16; dy = (tv >> 8) & 255; dx = tv & 255;
        } else {
          ic = k >> (2 * ls);
          int r2 = k & ((1 << (2 * ls)) - 1);
          dy = r2 >> ls; dx = r2 & ((1 << ls) - 1);
        }
        int ih = ihBase + dy, iw = iwBase + dx;
        if (ih >= 0 && ih < H && iw >= 0 && iw < W)
          v = in[inBase + ic * HW + ih * W + iw];
      }
      sA[kk][mm] = v;
    }
#pragma unroll
    for (int i = 0; i < 4; ++i) {
      int kk = kq * 4 + i, k = k0 + kk;
      int n = n0 + mm;
      float v = 0.0f;
      if (n < N && k < K) v = w[n * K + k];
      sB[kk][mm] = v;
    }
    __syncthreads();
#pragma unroll
    for (int kk = 0; kk < 16; ++kk) {
      float4 a4 = *(const float4*)&sA[kk][tm * 4];
      float4 b4 = *(const float4*)&sB[kk][tn * 4];
      acc[0][0] += a4.x * b4.x; acc[0][1] += a4.x * b4.y;
      acc[0][2] += a4.x * b4.z; acc[0][3] += a4.x * b4.w;
      acc[1][0] += a4.y * b4.x; acc[1][1] += a4.y * b4.y;
      acc[1][2] += a4.y * b4.z; acc[1][3] += a4.y * b4.w;
      acc[2][0] += a4.z * b4.x; acc[2][1] += a4.z * b4.y;
      acc[2][2] += a4.z * b4.z; acc[2][3] += a4.z * b4.w;
      acc[3][0] += a4.w * b4.x; acc[3][1] += a4.w * b4.y;
      acc[3][2] += a4.w * b4.z; acc[3][3] += a4.w * b4.w;
    }
  }
#pragma unroll
  for (int i = 0; i < 4; ++i) {
    int mI = m0 + tm * 4 + i;
    int bO = mI / OHW; int rr = mI - bO * OHW;
#pragma unroll
    for (int j = 0; j < 4; ++j) {
      int n = n0 + tn * 4 + j;
      if (n < N) {
        float v = acc[i][j] * bns[n] + bnb[n];
        if (GELU) v = gelu_f(v);
        if (TOOUT) {
          out[(bO * OHW + rr) * 768 + ch0 + n] = v;  // OHW==196
        } else {
          int oh2 = rr / OW, ow2 = rr - oh2 * OW;
          out[((bO * N + n) * OH + oh2) * OW + ow2] = v;
        }
      }
    }
  }
}

// ---------------------------------------------------------------------------
// NHWC bf16 implicit-GEMM conv via MFMA, v3:
//  - operands swapped (A=weights, B=pixels): lane holds 4 consecutive
//    channels per pixel -> uint2 epilogue stores (validated in R12).
//  - WREG=true: weight fragments hoisted into VGPRs ONCE before staging
//    (overlaps sA staging + barrier). MFMA loop = KSTEPS ds_read + NT*KSTEPS
//    MFMA, no in-loop weight traffic (fixes both R11's LDS-read bound and
//    R12's in-loop global-latency bound).
//  - WREG=false (large K): weights staged to LDS as before.
// ---------------------------------------------------------------------------
template<int CIN, int KS, int STRIDE, int PAD, int NN, int KP, bool GELU,
         bool WREG, int NVALID = NN>
__global__ __launch_bounds__(256) void nhwc_conv_mfma(
    const __hip_bfloat16* __restrict__ in, const __hip_bfloat16* __restrict__ wb,
    const float* __restrict__ bns, const float* __restrict__ bnb,
    __hip_bfloat16* __restrict__ out, int Hin, int Win, int OW, int OHW) {
  constexpr int K = KS * KS * CIN;
  constexpr int LROW = KP + 8;
  constexpr int NT = NN / 16;
  constexpr int KSTEPS = KP / 32;
  constexpr int SBROWS = WREG ? 1 : NN;
  __shared__ __align__(16) __hip_bfloat16 sA[64][LROW];
  __shared__ __align__(16) __hip_bfloat16 sB[SBROWS][LROW];
  const int tid = threadIdx.x;
  const int lane = tid & 63, wave = tid >> 6;
  const int fm = lane & 15, quad = lane >> 4;
  const float4 f4z = make_float4(0.f, 0.f, 0.f, 0.f);
  // ---- weight fragment prefetch (register path) — issued FIRST so the
  // global loads overlap the sA staging below.
  short8 wreg[WREG ? NT : 1][WREG ? KSTEPS : 1];
  if constexpr (WREG) {
#pragma unroll
    for (int m = 0; m < NT; ++m)
#pragma unroll
      for (int ks = 0; ks < KSTEPS; ++ks)
        wreg[m][ks] =
            *(const short8*)(wb + (size_t)(m * 16 + fm) * KP + ks * 32 + quad * 8);
  }
  // ---- stage A (pixels)
  if constexpr (CIN == 4) {
    const int m = tid & 63, tg = tid >> 6;
    const int mg = blockIdx.x * 64 + m;
    const int bI = mg / OHW; int pix = mg - bI * OHW;
    const int oh = pix / OW, ow = pix - oh * OW;
    for (int dy = tg; dy < KS; dy += 4) {
      const int ih = oh * STRIDE - PAD + dy;
      __hip_bfloat16* dst = &sA[m][dy * KS * 4];
#pragma unroll
      for (int j = 0; j < KS; ++j) {
        int iw = ow * STRIDE - PAD + j;
        uint2 v = make_uint2(0u, 0u);
        if (ih >= 0 && ih < Hin && iw >= 0 && iw < Win)
          v = *(const uint2*)(in + (((size_t)bI * Hin + ih) * Win + iw) * 4);
        *(uint2*)(dst + j * 4) = v;
      }
    }
    if (tg == 3) {
      for (int c = K; c < KP; c += 4) *(uint2*)&sA[m][c] = make_uint2(0u, 0u);
    }
  } else {
    const int m = tid & 63, dy = tid >> 6;
    const int mg = blockIdx.x * 64 + m;
    const int bI = mg / OHW; int pix = mg - bI * OHW;
    const int oh = pix / OW, ow = pix - oh * OW;
    if (dy < KS) {
      const int ih = oh * STRIDE - PAD + dy;
      __hip_bfloat16* dst = &sA[m][dy * KS * CIN];
      if (ih < 0 || ih >= Hin) {
#pragma unroll
        for (int i = 0; i < KS * CIN / 8; ++i) ((float4*)dst)[i] = f4z;
      } else {
        const __hip_bfloat16* srow = in + ((size_t)bI * Hin + ih) * Win * CIN;
#pragma unroll
        for (int j = 0; j < KS; ++j) {
          int iw = ow * STRIDE - PAD + j;
          if (PAD > 0 && (iw < 0 || iw >= Win)) {
#pragma unroll
            for (int i = 0; i < CIN / 8; ++i) ((float4*)(dst + j * CIN))[i] = f4z;
          } else {
            const float4* s4 = (const float4*)(srow + (size_t)iw * CIN);
#pragma unroll
            for (int i = 0; i < CIN / 8; ++i) ((float4*)(dst + j * CIN))[i] = s4[i];
          }
        }
      }
    } else if (K < KP) {
#pragma unroll
      for (int c = K; c < KP + 8; c += 8) *(float4*)&sA[m][c] = f4z;
    }
  }
  // ---- stage B (weights) — LDS path only
  if constexpr (!WREG) {
    constexpr int NV = NN * KP / 8;
    const float4* w4 = (const float4*)wb;
    for (int i = tid; i < NV; i += 256) {
      int n = i / (KP / 8), c = i - n * (KP / 8);
      *(float4*)&sB[n][c * 8] = w4[i];
    }
  }
  __syncthreads();
  // ---- MFMA: A = weights (rows = channels), B = pixels
  const int p = wave * 16 + fm;
  f32x4 acc[NT] = {};
#pragma unroll
  for (int ks = 0; ks < KSTEPS; ++ks) {
    short8 hb = *(const short8*)&sA[p][ks * 32 + quad * 8];
#pragma unroll
    for (int m = 0; m < NT; ++m) {
      short8 wa;
      if constexpr (WREG) {
        wa = wreg[m][ks];
      } else {
        wa = *(const short8*)&sB[m * 16 + fm][ks * 32 + quad * 8];
      }
      acc[m] = __builtin_amdgcn_mfma_f32_16x16x32_bf16(wa, hb, acc[m], 0, 0, 0);
    }
  }
  // ---- epilogue: lane = 1 pixel, channels m*16+quad*4..+3 -> uint2
  const int mg0 = blockIdx.x * 64 + p;
  const int bI = mg0 / OHW, pix = mg0 - bI * OHW;
  __hip_bfloat16* obase = out + ((size_t)bI * OHW + pix) * NVALID;
#pragma unroll
  for (int m = 0; m < NT; ++m) {
    int ch0m = m * 16 + quad * 4;
    if (ch0m < NVALID) {
      __hip_bfloat16 vb[4];
#pragma unroll
      for (int e = 0; e < 4; ++e) {
        int ch = ch0m + e;
        float v = acc[m][e] * bns[ch] + bnb[ch];
        if (GELU) v = gelu_f(v);
        vb[e] = (__hip_bfloat16)v;
      }
      *(uint2*)&obase[ch0m] = *(uint2*)vb;
    }
  }
}

// ---------------------------------------------------------------------------
// Fused RegionLayerDW for region2 (unchanged — validated)
// ---------------------------------------------------------------------------
__global__ __launch_bounds__(256, 4) void region2_mfma(
    const __hip_bfloat16* __restrict__ in, const float* __restrict__ dww,
    const float* __restrict__ s1v, const float* __restrict__ b1v,
    const __hip_bfloat16* __restrict__ pwb,
    const float* __restrict__ s2v, const float* __restrict__ b2v,
    __hip_bfloat16* __restrict__ out) {
  __shared__ __align__(16) __hip_bfloat16 sIn[10][10][56];
  __shared__ __align__(16) __hip_bfloat16 sH[64][64];
  __shared__ __align__(16) __hip_bfloat16 sW[48][64];
  __shared__ float sDW[48][9];
  __shared__ float sS1[48], sB1[48], sS2[48], sB2[48];
  const int t = blockIdx.x, sb = blockIdx.y, b = blockIdx.z;
  const int gy = t >> 2, gx = t & 3;
  const int py0 = (sb / 7) * 8, px0 = (sb % 7) * 8;
  const int Y0 = gy * 56, X0 = gx * 56;
  const int tid = threadIdx.x;
  for (int i = tid; i < 48 * 8; i += 256) {
    int n = i >> 3, g = i & 7;
    float4 v = *(const float4*)&pwb[(size_t)(t * 48 + n) * 64 + g * 8];
    *(float4*)&sW[n][((g ^ (n & 7)) * 8)] = v;
  }
  for (int i = tid; i < 432; i += 256) ((float*)sDW)[i] = dww[t * 432 + i];
  if (tid < 48) {
    sS1[tid] = s1v[t * 48 + tid]; sB1[tid] = b1v[t * 48 + tid];
    sS2[tid] = s2v[t * 48 + tid]; sB2[tid] = b2v[t * 48 + tid];
  }
  for (int i = tid; i < 600; i += 256) {
    int px = i / 6, grp = i - px * 6;
    int r = px / 10, c = px - r * 10;
    int ly = py0 + r - 1, lx = px0 + c - 1;
    uint4 v = make_uint4(0u, 0u, 0u, 0u);
    if (ly >= 0 && ly < 56 && lx >= 0 && lx < 56)
      v = *(const uint4*)(in + (((size_t)b * 224 + Y0 + ly) * 224 + X0 + lx) * 48 +
                          grp * 8);
    *(uint4*)&sIn[r][c][grp * 8] = v;
  }
  __syncthreads();
  if (tid < 192) {
    const int cg = tid >> 4;
    const int rem = tid & 15;
    const int col = rem >> 1;
    const int rh = rem & 1;
    const int ch0 = cg * 4;
    float wv[4][9], s14[4], b14[4];
#pragma unroll
    for (int c4 = 0; c4 < 4; ++c4) {
#pragma unroll
      for (int q = 0; q < 9; ++q) wv[c4][q] = sDW[ch0 + c4][q];
      s14[c4] = sS1[ch0 + c4]; b14[c4] = sB1[ch0 + c4];
    }
    float win[3][12];
#pragma unroll
    for (int rr = 0; rr < 6; ++rr) {
      int r = rh * 4 + rr;
      float* wr = win[rr % 3];
#pragma unroll
      for (int cc = 0; cc < 3; ++cc) {
        uint2 u = *(const uint2*)&sIn[r][col + cc][ch0];
        wr[cc * 4 + 0] = __uint_as_float(u.x << 16);
        wr[cc * 4 + 1] = __uint_as_float(u.x & 0xffff0000u);
        wr[cc * 4 + 2] = __uint_as_float(u.y << 16);
        wr[cc * 4 + 3] = __uint_as_float(u.y & 0xffff0000u);
      }
      if (rr >= 2) {
        const float* ra = win[(rr - 2) % 3];
        const float* rb = win[(rr - 1) % 3];
        const float* rc = win[rr % 3];
        int px = (rh * 4 + rr - 2) * 8 + col;
        __hip_bfloat16 hv[4];
#pragma unroll
        for (int c4 = 0; c4 < 4; ++c4) {
          float a = ra[c4] * wv[c4][0] + ra[4 + c4] * wv[c4][1] + ra[8 + c4] * wv[c4][2]
                  + rb[c4] * wv[c4][3] + rb[4 + c4] * wv[c4][4] + rb[8 + c4] * wv[c4][5]
                  + rc[c4] * wv[c4][6] + rc[4 + c4] * wv[c4][7] + rc[8 + c4] * wv[c4][8];
          hv[c4] = (__hip_bfloat16)gelu_f(a * s14[c4] + b14[c4]);
        }
        *(uint2*)&sH[px][((cg >> 1) ^ (px & 7)) * 8 + (cg & 1) * 4] = *(uint2*)hv;
      }
    }
  } else {
    for (int i = tid - 192; i < 128; i += 64) {
      int px = i >> 1, g = 6 + (i & 1);
      *(float4*)&sH[px][(g ^ (px & 7)) * 8] = make_float4(0.f, 0.f, 0.f, 0.f);
    }
  }
  __syncthreads();
  const int wave = tid >> 6, lane = tid & 63;
  const int fm = lane & 15, quad = lane >> 4;
  const int px = wave * 16 + fm, pxk = px & 7;
  f32x4 acc[3] = {};
#pragma unroll
  for (int ks = 0; ks < 2; ++ks) {
    short8 hb = *(const short8*)&sH[px][((ks * 4 + quad) ^ pxk) * 8];
#pragma unroll
    for (int m = 0; m < 3; ++m) {
      int wr = m * 16 + fm;
      short8 wa = *(const short8*)&sW[wr][((ks * 4 + quad) ^ (wr & 7)) * 8];
      acc[m] = __builtin_amdgcn_mfma_f32_16x16x32_bf16(wa, hb, acc[m], 0, 0, 0);
    }
  }
  const int row = px >> 3, col = px & 7;
  __hip_bfloat16* obase =
      out + (((size_t)b * 224 + Y0 + py0 + row) * 224 + X0 + px0 + col) * 48;
#pragma unroll
  for (int m = 0; m < 3; ++m) {
    int ch0m = m * 16 + quad * 4;
    uint2 ru = *(const uint2*)&sIn[row + 1][col + 1][ch0m];
    float res[4];
    res[0] = __uint_as_float(ru.x << 16);
    res[1] = __uint_as_float(ru.x & 0xffff0000u);
    res[2] = __uint_as_float(ru.y << 16);
    res[3] = __uint_as_float(ru.y & 0xffff0000u);
    __hip_bfloat16 vb[4];
#pragma unroll
    for (int e = 0; e < 4; ++e) {
      int ch = ch0m + e;
      float v = acc[m][e] * sS2[ch] + sB2[ch] + res[e];
      vb[e] = (__hip_bfloat16)gelu_f(v);
    }
    *(uint2*)&obase[ch0m] = *(uint2*)vb;
  }
}

// ---------------------------------------------------------------------------
// Fused RegionLayerDW for region1 (unchanged — validated)
// ---------------------------------------------------------------------------
__global__ __launch_bounds__(256, 4) void region1_mfma(
    const __hip_bfloat16* __restrict__ in, const float* __restrict__ dww,
    const float* __restrict__ s1v, const float* __restrict__ b1v,
    const __hip_bfloat16* __restrict__ pwb,
    const float* __restrict__ s2v, const float* __restrict__ b2v,
    __hip_bfloat16* __restrict__ out) {
  __shared__ __align__(16) __hip_bfloat16 sIn[10][10][24];
  __shared__ __align__(16) __hip_bfloat16 sH[64][32];
  __shared__ __align__(16) __hip_bfloat16 sW[32][32];
  __shared__ float sDW[24][9];
  __shared__ float sS1[24], sB1[24], sS2[24], sB2[24];
  const int t = blockIdx.x, sb = blockIdx.y, b = blockIdx.z;
  const int gy = t / 7, gx = t % 7;
  const int py0 = (sb >> 2) * 8, px0 = (sb & 3) * 8;
  const int Y0 = gy * 32, X0 = gx * 32;
  const int tid = threadIdx.x;
  for (int i = tid; i < 128; i += 256) {
    int n = i >> 2, g = i & 3;
    float4 v = make_float4(0.f, 0.f, 0.f, 0.f);
    if (n < 24) v = *(const float4*)&pwb[(size_t)(t * 24 + n) * 32 + g * 8];
    *(float4*)&sW[n][(g ^ (n & 3)) * 8] = v;
  }
  for (int i = tid; i < 216; i += 256) ((float*)sDW)[i] = dww[t * 216 + i];
  if (tid < 24) {
    sS1[tid] = s1v[t * 24 + tid]; sB1[tid] = b1v[t * 24 + tid];
    sS2[tid] = s2v[t * 24 + tid]; sB2[tid] = b2v[t * 24 + tid];
  }
  for (int i = tid; i < 300; i += 256) {
    int px = i / 3, grp = i - px * 3;
    int r = px / 10, c = px - r * 10;
    int ly = py0 + r - 1, lx = px0 + c - 1;
    uint4 v = make_uint4(0u, 0u, 0u, 0u);
    if (ly >= 0 && ly < 32 && lx >= 0 && lx < 32)
      v = *(const uint4*)(in + (((size_t)b * 224 + Y0 + ly) * 224 + X0 + lx) * 24 +
                          grp * 8);
    *(uint4*)&sIn[r][c][grp * 8] = v;
  }
  __syncthreads();
  if (tid < 192) {
    const int cg = tid >> 5;
    const int rem = tid & 31;
    const int col = rem >> 2;
    const int rq = rem & 3;
    const int ch0 = cg * 4;
    float wv[4][9], s14[4], b14[4];
#pragma unroll
    for (int c4 = 0; c4 < 4; ++c4) {
#pragma unroll
      for (int q = 0; q < 9; ++q) wv[c4][q] = sDW[ch0 + c4][q];
      s14[c4] = sS1[ch0 + c4]; b14[c4] = sB1[ch0 + c4];
    }
    float win[3][12];
#pragma unroll
    for (int rr = 0; rr < 4; ++rr) {
      int r = rq * 2 + rr;
      float* wr = win[rr % 3];
#pragma unroll
      for (int cc = 0; cc < 3; ++cc) {
        uint2 u = *(const uint2*)&sIn[r][col + cc][ch0];
        wr[cc * 4 + 0] = __uint_as_float(u.x << 16);
        wr[cc * 4 + 1] = __uint_as_float(u.x & 0xffff0000u);
        wr[cc * 4 + 2] = __uint_as_float(u.y << 16);
        wr[cc * 4 + 3] = __uint_as_float(u.y & 0xffff0000u);
      }
      if (rr >= 2) {
        const float* ra = win[(rr - 2) % 3];
        const float* rb = win[(rr - 1) % 3];
        const float* rc = win[rr % 3];
        int px = (rq * 2 + rr - 2) * 8 + col;
        __hip_bfloat16 hv[4];
#pragma unroll
        for (int c4 = 0; c4 < 4; ++c4) {
          float a = ra[c4] * wv[c4][0] + ra[4 + c4] * wv[c4][1] + ra[8 + c4] * wv[c4][2]
                  + rb[c4] * wv[c4][3] + rb[4 + c4] * wv[c4][4] + rb[8 + c4] * wv[c4][5]
                  + rc[c4] * wv[c4][6] + rc[4 + c4] * wv[c4][7] + rc[8 + c4] * wv[c4][8];
          hv[c4] = (__hip_bfloat16)gelu_f(a * s14[c4] + b14[c4]);
        }
        *(uint2*)&sH[px][((cg >> 1) ^ (px & 3)) * 8 + (cg & 1) * 4] = *(uint2*)hv;
      }
    }
  } else {
    int px = tid - 192;
    *(float4*)&sH[px][(3 ^ (px & 3)) * 8] = make_float4(0.f, 0.f, 0.f, 0.f);
  }
  __syncthreads();
  const int wave = tid >> 6, lane = tid & 63;
  const int fm = lane & 15, quad = lane >> 4;
  const int px = wave * 16 + fm;
  short8 hb = *(const short8*)&sH[px][(quad ^ (px & 3)) * 8];
  f32x4 acc[2] = {};
#pragma unroll
  for (int m = 0; m < 2; ++m) {
    int wr = m * 16 + fm;
    short8 wa = *(const short8*)&sW[wr][(quad ^ (wr & 3)) * 8];
    acc[m] = __builtin_amdgcn_mfma_f32_16x16x32_bf16(wa, hb, acc[m], 0, 0, 0);
  }
  const int row = px >> 3, col = px & 7;
  __hip_bfloat16* obase =
      out + (((size_t)b * 224 + Y0 + py0 + row) * 224 + X0 + px0 + col) * 24;
#pragma unroll
  for (int m = 0; m < 2; ++m) {
    int ch0m = m * 16 + quad * 4;
    if (ch0m < 24) {
      uint2 ru = *(const uint2*)&sIn[row + 1][col + 1][ch0m];
      float res[4];
      res[0] = __uint_as_float(ru.x << 16);
      res[1] = __uint_as_float(ru.x & 0xffff0000u);
      res[2] = __uint_as_float(ru.y << 16);
      res[3] = __uint_as_float(ru.y & 0xffff0000u);
      __hip_bfloat16 vb[4];
#pragma unroll
      for (int e = 0; e < 4; ++e) {
        int ch = ch0m + e;
        float v = acc[m][e] * sS2[ch] + sB2[ch] + res[e];
        vb[e] = (__hip_bfloat16)gelu_f(v);
      }
      *(uint2*)&obase[ch0m] = *(uint2*)vb;
    }
  }
}

// ---------------------------------------------------------------------------
// Patch-GEMM via MFMA (b3 + branch2-conv2). Unchanged.
// ---------------------------------------------------------------------------
template<int PS, int IMGW, int KTOT, int KSL, bool ATOMIC>
__global__ __launch_bounds__(256) void patch_gemm_mfma(
    const __hip_bfloat16* __restrict__ A, const __hip_bfloat16* __restrict__ Wb,
    const float* __restrict__ scale, const float* __restrict__ bias,
    float* __restrict__ out, int M, int ch0) {
  constexpr int RUN = PS * 48;
  __shared__ __align__(16) __hip_bfloat16 sA[64][64];
  __shared__ __align__(16) __hip_bfloat16 sB[64][64];
  const int tid = threadIdx.x;
  const int m0 = blockIdx.x * 64, n0 = blockIdx.y * 64;
  const int kBase = blockIdx.z * KSL;
  const int mi = tid >> 2, seg = tid & 3;
  int m = m0 + mi; int mc = (m < M) ? m : (M - 1);
  int bI = mc / 196; int r = mc - bI * 196;
  int oh = r / 14, ow = r - oh * 14;
  const __hip_bfloat16* Abase =
      A + (((size_t)bI * IMGW + oh * PS) * IMGW + ow * PS) * 48;
  const __hip_bfloat16* Wrow = Wb + (size_t)(n0 + mi) * KTOT;
  const int wave = tid >> 6, lane = tid & 63;
  const int wm = (wave & 1) * 32, wn = (wave >> 1) * 32;
  const int fm = lane & 15, quad = lane >> 4;
  const int sw = fm & 7;
  f32x4 acc[2][2] = {};
  for (int k0 = kBase; k0 < kBase + KSL; k0 += 64) {
    int dy = k0 / RUN, rem = k0 - dy * RUN;
    __syncthreads();
    {
      const __hip_bfloat16* p = Abase + (size_t)dy * IMGW * 48 + rem + seg * 16;
      float4 v0 = *(const float4*)p;
      float4 v1 = *(const float4*)(p + 8);
      int key = mi & 7;
      *(float4*)&sA[mi][((seg * 2) ^ key) * 8] = v0;
      *(float4*)&sA[mi][((seg * 2 + 1) ^ key) * 8] = v1;
      const __hip_bfloat16* q = Wrow + k0 + seg * 16;
      float4 w0 = *(const float4*)q;
      float4 w1 = *(const float4*)(q + 8);
      *(float4*)&sB[mi][((seg * 2) ^ key) * 8] = w0;
      *(float4*)&sB[mi][((seg * 2 + 1) ^ key) * 8] = w1;
    }
    __syncthreads();
#pragma unroll
    for (int ks = 0; ks < 2; ++ks) {
      int cg = (ks * 4 + quad) ^ sw;
#pragma unroll
      for (int i = 0; i < 2; ++i) {
        short8 a = *(const short8*)&sA[wm + i * 16 + fm][cg * 8];
#pragma unroll
        for (int j = 0; j < 2; ++j) {
          short8 b = *(const short8*)&sB[wn + j * 16 + fm][cg * 8];
          acc[i][j] = __builtin_amdgcn_mfma_f32_16x16x32_bf16(a, b, acc[i][j], 0, 0, 0);
        }
      }
    }
  }
#pragma unroll
  for (int i = 0; i < 2; ++i) {
#pragma unroll
    for (int j = 0; j < 2; ++j) {
      int gn = n0 + wn + j * 16 + fm;
      float sc = scale[gn];
#pragma unroll
      for (int e = 0; e < 4; ++e) {
        int gm = m0 + wm + i * 16 + quad * 4 + e;
        if (gm < M) {
          if (ATOMIC)
            atomicAdd(&out[(size_t)gm * 768 + ch0 + gn], acc[i][j][e] * sc);
          else
            out[(size_t)gm * 768 + ch0 + gn] = acc[i][j][e] * sc + bias[gn];
        }
      }
    }
  }
}

__global__ void init_b3(float* __restrict__ out, const float* __restrict__ bias) {
  int i = blockIdx.x * 256 + threadIdx.x;
  if (i < 16 * 196 * 256) {
    int n = i & 255, bp = i >> 8;
    out[bp * 768 + 512 + n] = bias[n];
  }
}

// OIHW fp32 -> [N][KP] bf16 with k=(dy*ks+dx)*Cin+ic, zero-padded to KP
__global__ void reorder_w_k(const float* __restrict__ w, __hip_bfloat16* __restrict__ o,
                            int N, int Cin, int ks, int KP) {
  int i = blockIdx.x * 256 + threadIdx.x;
  if (i >= N * KP) return;
  int n = i / KP, k = i - n * KP;
  float v = 0.f;
  int K = ks * ks * Cin;
  if (k < K) {
    int dy = k / (ks * Cin); int r = k - dy * ks * Cin;
    int dx = r / Cin, ic = r - dx * Cin;
    v = w[((n * Cin + ic) * ks + dy) * ks + dx];
  }
  o[i] = (__hip_bfloat16)v;
}

// OIHW fp32 -> [Nout][KP] bf16 with channel padding
__global__ void reorder_w4(const float* __restrict__ w, __hip_bfloat16* __restrict__ o,
                           int Nout, int Nreal, int Cp, int Cr, int ks, int KP) {
  int i = blockIdx.x * 256 + threadIdx.x;
  if (i >= Nout * KP) return;
  int n = i / KP, k = i - n * KP;
  float v = 0.f;
  if (n < Nreal && k < ks * ks * Cp) {
    int dy = k / (ks * Cp); int r = k - dy * ks * Cp;
    int dx = r / Cp, ic = r - dx * Cp;
    if (ic < Cr) v = w[((n * Cr + ic) * ks + dy) * ks + dx];
  }
  o[i] = (__hip_bfloat16)v;
}

// region2 pw weights [16][48][48] fp32 -> [16][48][64] bf16 (K-padded)
__global__ void rw_pw(const float* __restrict__ pw, __hip_bfloat16* __restrict__ o) {
  int i = blockIdx.x * 256 + threadIdx.x;
  if (i >= 16 * 48 * 64) return;
  int t = i / 3072, r = i - t * 3072;
  int n = r >> 6, k = r & 63;
  float v = (k < 48) ? pw[(t * 48 + n) * 48 + k] : 0.f;
  o[i] = (__hip_bfloat16)v;
}

// region1 pw weights [49][24][24] fp32 -> [49][24][32] bf16 (K-padded)
__global__ void rw_pw1(const float* __restrict__ pw, __hip_bfloat16* __restrict__ o) {
  int i = blockIdx.x * 256 + threadIdx.x;
  if (i >= 49 * 24 * 32) return;
  int t = i / 768, r = i - t * 768;
  int n = r >> 5, k = r & 31;
  float v = (k < 24) ? pw[(t * 24 + n) * 24 + k] : 0.f;
  o[i] = (__hip_bfloat16)v;
}

// x [16,3,224,224] fp32 -> [16,224,224,4] bf16 (ch3 = 0)
__global__ void xcvt(const float* __restrict__ x, __hip_bfloat16* __restrict__ o) {
  int i = blockIdx.x * 256 + threadIdx.x;
  if (i >= 802816) return;
  int b = i / 50176, p = i - b * 50176;
  const float* src = x + (size_t)b * 150528 + p;
  __hip_bfloat16 v[4];
  v[0] = (__hip_bfloat16)src[0];
  v[1] = (__hip_bfloat16)src[50176];
  v[2] = (__hip_bfloat16)src[100352];
  v[3] = (__hip_bfloat16)0.0f;
  *(uint2*)&o[(size_t)i * 4] = *(uint2*)v;
}

// ---------------------------------------------------------------------------
extern "C" void kernel_launch(void* const* d_in, const int* in_sizes, int n_in,
                              void* d_out, int out_size, void* d_ws, size_t ws_size,
                              hipStream_t stream) {
  const float* x     = (const float*)d_in[0];
  const float* r1_w  = (const float*)d_in[1];
  const float* r1_s  = (const float*)d_in[2];
  const float* r1_b  = (const float*)d_in[3];
  const float* r1_dw = (const float*)d_in[4];
  const float* r1_s1 = (const float*)d_in[5];
  const float* r1_b1 = (const float*)d_in[6];
  const float* r1_pw = (const float*)d_in[7];
  const float* r1_s2 = (const float*)d_in[8];
  const float* r1_b2 = (const float*)d_in[9];
  const float* r2_w  = (const float*)d_in[10];
  const float* r2_s  = (const float*)d_in[11];
  const float* r2_b  = (const float*)d_in[12];
  const float* r2_dw = (const float*)d_in[13];
  const float* r2_s1 = (const float*)d_in[14];
  const float* r2_b1 = (const float*)d_in[15];
  const float* r2_pw = (const float*)d_in[16];
  const float* r2_s2 = (const float*)d_in[17];
  const float* r2_b2 = (const float*)d_in[18];
  const float* h1_w1 = (const float*)d_in[19];
  const float* h1_s1 = (const float*)d_in[20];
  const float* h1_b1 = (const float*)d_in[21];
  const float* h1_w2 = (const float*)d_in[22];
  const float* h1_s2 = (const float*)d_in[23];
  const float* h1_b2 = (const float*)d_in[24];
  const float* h1_w3 = (const float*)d_in[25];
  const float* h1_s3 = (const float*)d_in[26];
  const float* h1_b3 = (const float*)d_in[27];
  const float* h2_w1 = (const float*)d_in[28];
  const float* h2_s1 = (const float*)d_in[29];
  const float* h2_b1 = (const float*)d_in[30];
  const float* h2_w2 = (const float*)d_in[31];
  const float* h2_s2 = (const float*)d_in[32];
  const float* h2_b2 = (const float*)d_in[33];
  const float* h3_w  = (const float*)d_in[34];
  const float* h3_s  = (const float*)d_in[35];
  const float* h3_b  = (const float*)d_in[36];
  float* out = (float*)d_out;

  // Workspace (float-slot offsets). FULL-BATCH, peak ~223 MB < 256 MiB.
  float* F = (float*)d_ws;
  __hip_bfloat16* R1b   = (__hip_bfloat16*)F;                    // [16,224,224,24]
  __hip_bfloat16* C5b   = (__hip_bfloat16*)(F + 9633792);        // [16,224,224,24]
  __hip_bfloat16* T1b   = (__hip_bfloat16*)(F + 9633792);        // [16,224,224,48]
  __hip_bfloat16* T2b   = (__hip_bfloat16*)(F + 28901376);       // [16,224,224,48]
  __hip_bfloat16* h3wb  = (__hip_bfloat16*)(F + 48168960);       // [256][12288]
  __hip_bfloat16* r2wb  = (__hip_bfloat16*)(F + 49741824);       // [48][224]
  __hip_bfloat16* h2w1b = (__hip_bfloat16*)(F + 49747200);       // [48][384]
  __hip_bfloat16* pw2wb = (__hip_bfloat16*)(F + 49756416);       // [16][48][64]
  __hip_bfloat16* r1wb  = (__hip_bfloat16*)(F + 49780992);       // [32][128]
  __hip_bfloat16* h2w2b = (__hip_bfloat16*)(F + 49783040);       // [256][768]
  __hip_bfloat16* xb    = (__hip_bfloat16*)(F + 49881344);       // [16,224,224,4]
  __hip_bfloat16* S1b   = (__hip_bfloat16*)(F + 51486976);       // [16,56,56,48]
  float* S1             = F + 52691200;                          // [16,48,56,56]
  float* S2             = F + 55099648;                          // [16,48,28,28]
  __hip_bfloat16* pw1wb = (__hip_bfloat16*)(F + 55701760);       // [49][24][32]

  dim3 blk(256);

  // ---- input conversion + weight reorders
  xcvt<<<dim3(3136), blk, 0, stream>>>(x, xb);
  reorder_w_k<<<dim3(12288), blk, 0, stream>>>(h3_w, h3wb, 256, 48, 16, 12288);
  reorder_w_k<<<dim3(42), blk, 0, stream>>>(r2_w, r2wb, 48, 24, 3, 224);
  reorder_w_k<<<dim3(72), blk, 0, stream>>>(h2_w1, h2w1b, 48, 24, 4, 384);
  reorder_w_k<<<dim3(768), blk, 0, stream>>>(h2_w2, h2w2b, 256, 48, 4, 768);
  reorder_w4<<<dim3(16), blk, 0, stream>>>(r1_w, r1wb, 32, 24, 4, 3, 5, 128);
  rw_pw<<<dim3(192), blk, 0, stream>>>(r2_pw, pw2wb);
  rw_pw1<<<dim3(147), blk, 0, stream>>>(r1_pw, pw1wb);

  // ---- region1 chain, FULL BATCH: conv5 MFMA -> C5b NHWC bf16, region1 -> R1b
  nhwc_conv_mfma<4, 5, 1, 2, 32, 128, true, true, 24><<<dim3(12544), blk, 0, stream>>>(
      xb, r1wb, r1_s, r1_b, C5b, 224, 224, 224, 50176);
  region1_mfma<<<dim3(49, 16, 16), blk, 0, stream>>>(
      C5b, r1_dw, r1_s1, r1_b1, pw1wb, r1_s2, r1_b2, R1b);
  // ---- branch2: R1b -> S1b bf16 NHWC -> out[ch 256:512]
  nhwc_conv_mfma<24, 4, 4, 0, 48, 384, true, false><<<dim3(784), blk, 0, stream>>>(
      R1b, h2w1b, h2_s1, h2_b1, S1b, 224, 224, 56, 3136);
  patch_gemm_mfma<4, 56, 768, 768, false><<<dim3(49, 4, 1), blk, 0, stream>>>(
      S1b, h2w2b, h2_s2, h2_b2, out, 3136, 256);
  // ---- branch1: x -> S1 -> S2 -> out[ch 0:256] (fp32, small)
  convgemm_k<false, true, false><<<dim3(784, 1), blk, 0, stream>>>(
      x, h1_w1, h1_s1, h1_b1, S1, 3, 224, 224, 4, 4, 0, 2, 56, 56, 48, 48, 0);
  convgemm_k<false, true, false><<<dim3(196, 1), blk, 0, stream>>>(
      S1, h1_w2, h1_s2, h1_b2, S2, 48, 56, 56, 2, 2, 0, 1, 28, 28, 48, 192, 0);
  convgemm_k<false, false, true><<<dim3(49, 4), blk, 0, stream>>>(
      S2, h1_w3, h1_s3, h1_b3, out, 48, 28, 28, 2, 2, 0, 1, 14, 14, 256, 192, 0);
  // ---- branch3 FULL BATCH: conv3 -> region2 -> b3 patch-GEMM (split-K)
  init_b3<<<dim3(3136), blk, 0, stream>>>(out, h3_b);
  nhwc_conv_mfma<24, 3, 1, 1, 48, 224, true, true><<<dim3(12544), blk, 0, stream>>>(
      R1b, r2wb, r2_s, r2_b, T1b, 224, 224, 224, 50176);
  region2_mfma<<<dim3(16, 49, 16), blk, 0, stream>>>(
      T1b, r2_dw, r2_s1, r2_b1, pw2wb, r2_s2, r2_b2, T2b);
  patch_gemm_mfma<16, 224, 12288, 1536, true><<<dim3(49, 4, 8), blk, 0, stream>>>(
      T2b, h3wb, h3_s, h3_b, out, 3136, 512);
  (void)in_sizes; (void)n_in; (void)out_size; (void)ws_size;
}